// Round 1
// baseline (693.617 us; speedup 1.0000x reference)
//
#include <hip/hip_runtime.h>
#include <math.h>

#define CDIM 256
#define HW 3136
#define M_TOT 100352   // 32*3136
#define HID 1024

typedef __attribute__((ext_vector_type(4))) float f32x4;
typedef __attribute__((ext_vector_type(8))) short bf16x8;
typedef __attribute__((ext_vector_type(4))) short bf16x4;

__device__ __forceinline__ unsigned short f2bf(float f){
  unsigned int u = __float_as_uint(f);
  u += 0x7FFFu + ((u >> 16) & 1u);
  return (unsigned short)(u >> 16);
}

// ---------------- prep: w1t[f][c] = w1[c][f]; w2t[c][f] = w2[f][c]  (bf16)
__global__ __launch_bounds__(256) void prep_kernel(
    const float* __restrict__ w1, const float* __restrict__ w2,
    unsigned short* __restrict__ w1t, unsigned short* __restrict__ w2t){
  int i = blockIdx.x * 256 + threadIdx.x;
  if (i < 262144){
    int f = i >> 8, c = i & 255;
    w1t[i] = f2bf(w1[c * 1024 + f]);
  } else {
    int j = i - 262144;
    int c = j >> 10, f = j & 1023;
    w2t[j] = f2bf(w2[f * 256 + c]);
  }
}

// ---------------- depthwise 7x7 conv + bias -> t0 (NCHW fp32, = d_out scratch)
__global__ __launch_bounds__(256) void conv_kernel(
    const float* __restrict__ x, const float* __restrict__ cw,
    const float* __restrict__ cb, float* __restrict__ t0){
  int bc = blockIdx.x;          // b*256 + c
  int c = bc & 255;
  int t = threadIdx.x;
  int h = t >> 2;
  int w0 = (t & 3) * 14;
  float wt[49];
  #pragma unroll
  for (int k = 0; k < 49; ++k) wt[k] = cw[c * 49 + k];
  float bias = cb[c];
  if (h >= 56) return;
  const float* xp = x + (long)bc * HW;
  float acc[14];
  #pragma unroll
  for (int ww = 0; ww < 14; ++ww) acc[ww] = bias;
  #pragma unroll
  for (int i = 0; i < 7; ++i){
    int hh = h - 3 + i;
    if (hh >= 0 && hh < 56){
      float seg[20];
      #pragma unroll
      for (int k = 0; k < 20; ++k){
        int col = w0 - 3 + k;
        seg[k] = (col >= 0 && col < 56) ? xp[hh * 56 + col] : 0.0f;
      }
      #pragma unroll
      for (int j = 0; j < 7; ++j){
        #pragma unroll
        for (int ww = 0; ww < 14; ++ww)
          acc[ww] = fmaf(seg[ww + j], wt[i * 7 + j], acc[ww]);
      }
    }
  }
  float* op = t0 + (long)bc * HW + h * 56 + w0;
  #pragma unroll
  for (int ww = 0; ww < 14; ++ww) op[ww] = acc[ww];
}

// ---------------- LayerNorm over C -> y[pos][c] bf16
__global__ __launch_bounds__(256) void ln_kernel(
    const float* __restrict__ t0, const float* __restrict__ lng,
    const float* __restrict__ lnb, unsigned short* __restrict__ y){
  int wv = threadIdx.x >> 6, lane = threadIdx.x & 63;
  int pos0 = blockIdx.x * 256 + wv * 64;       // 64-pos tile never straddles an image (3136 % 64 == 0)
  int b = pos0 / HW;
  int hw0 = pos0 - b * HW;
  const float* tp = t0 + (long)b * CDIM * HW + hw0;
  float s = 0.f, q = 0.f;
  #pragma unroll 8
  for (int c = 0; c < 256; ++c){
    float v = tp[c * HW + lane];
    s += v; q = fmaf(v, v, q);
  }
  float mu = s * (1.0f/256.0f);
  float var = q * (1.0f/256.0f) - mu * mu;
  float rs = rsqrtf(var + 1e-6f);
  for (int cc = 0; cc < 4; ++cc){
    int c = cc * 64 + lane;
    float gc = lng[c], bc = lnb[c];
    const float* tpc = tp + c * HW;
    unsigned short* yp = y + (long)pos0 * 256 + c;
    for (int p = 0; p < 64; ++p){
      float mu_p = __shfl(mu, p);
      float rs_p = __shfl(rs, p);
      float v = tpc[p];
      yp[p * 256] = f2bf((v - mu_p) * rs_p * gc + bc);
    }
  }
}

// ---------------- fused MLP: y[128 rows] @ w1 -> gelu -> @ w2 -> out (NCHW)
#define LDS_YA 0
#define LDS_W1 66560
#define LDS_W2 99840
#define LDS_H  134656
#define LDS_TOT 153088

__device__ __forceinline__ void load_lds16(const void* g, void* l){
  __builtin_amdgcn_global_load_lds(
      (const __attribute__((address_space(1))) unsigned int*)g,
      (__attribute__((address_space(3))) unsigned int*)l, 16, 0, 0);
}

__global__ __launch_bounds__(512, 2) void mlp_kernel(
    const unsigned short* __restrict__ y, const unsigned short* __restrict__ w1t,
    const unsigned short* __restrict__ w2t, const float* __restrict__ b1,
    const float* __restrict__ b2, float* __restrict__ out){
  __shared__ __align__(16) unsigned char smem[LDS_TOT];
  const int tid = threadIdx.x;
  const int wv = tid >> 6, lane = tid & 63;
  const int lr = lane & 15, lq = lane >> 4;
  const int blk = blockIdx.x;

  // stage A-tile: y rows blk*128..+127, 2 rows (1KB) per inst, pad 16B per group
  {
    const unsigned char* ybase = (const unsigned char*)(y + (long)blk * 128 * 256);
    #pragma unroll
    for (int r = 0; r < 8; ++r){
      int g = wv * 8 + r;
      load_lds16(ybase + g * 1024 + lane * 16, smem + LDS_YA + g * 1040);
    }
  }

  const int s1 = wv & 1, q1 = wv >> 1;   // phase1: f-half (32), m-quarter (32)
  const int s2 = wv & 3, q2 = wv >> 2;   // phase2: c-quarter (64), m-half (64)
  const int f0w = s1 * 32, m0w1 = q1 * 32;
  const int c0w = s2 * 64, m0w2 = q2 * 64;

  f32x4 acc2[4][4];
  #pragma unroll
  for (int a = 0; a < 4; ++a)
    #pragma unroll
    for (int bb = 0; bb < 4; ++bb) acc2[a][bb] = (f32x4){0.f,0.f,0.f,0.f};

  for (int ch = 0; ch < 16; ++ch){
    // stage w1 chunk (rows f = ch*64..+63) via global_load_lds
    {
      const unsigned char* wbase = (const unsigned char*)(w1t + (long)ch * 64 * 256);
      #pragma unroll
      for (int r = 0; r < 4; ++r){
        int g = wv * 4 + r;
        load_lds16(wbase + g * 1024 + lane * 16, smem + LDS_W1 + g * 1040);
      }
    }
    // stage w2 chunk (all 256 c, f = ch*64..+63) via VGPR roundtrip into padded layout
    {
      #pragma unroll
      for (int k = 0; k < 4; ++k){
        int crow = wv * 32 + k * 8 + (lane >> 3);
        int fcol8 = (lane & 7);
        const unsigned char* src =
            (const unsigned char*)(w2t + (long)crow * 1024 + ch * 64) + fcol8 * 16;
        bf16x8 v = *(const bf16x8*)src;
        *(bf16x8*)(smem + LDS_W2 + (crow >> 1) * 272 + (crow & 1) * 128 + fcol8 * 16) = v;
      }
    }
    __syncthreads();

    // phase 1: P^T[f][m] = w1t . y^T   (A = w1 frag rows=f, B = y frag n=m)
    f32x4 acc1[2][2];
    #pragma unroll
    for (int a = 0; a < 2; ++a)
      #pragma unroll
      for (int bb = 0; bb < 2; ++bb) acc1[a][bb] = (f32x4){0.f,0.f,0.f,0.f};
    #pragma unroll
    for (int ks = 0; ks < 8; ++ks){
      int kb = ks * 32 + lq * 8;
      bf16x8 yf[2], wf[2];
      #pragma unroll
      for (int mt = 0; mt < 2; ++mt){
        int m = m0w1 + mt * 16 + lr;
        yf[mt] = *(const bf16x8*)(smem + LDS_YA + (m >> 1) * 1040 + (m & 1) * 512 + kb * 2);
      }
      #pragma unroll
      for (int ft = 0; ft < 2; ++ft){
        int fl = f0w + ft * 16 + lr;
        wf[ft] = *(const bf16x8*)(smem + LDS_W1 + (fl >> 1) * 1040 + (fl & 1) * 512 + kb * 2);
      }
      #pragma unroll
      for (int ft = 0; ft < 2; ++ft)
        #pragma unroll
        for (int mt = 0; mt < 2; ++mt)
          acc1[ft][mt] = __builtin_amdgcn_mfma_f32_16x16x32_bf16(wf[ft], yf[mt], acc1[ft][mt], 0, 0, 0);
    }
    // bias + exact GELU -> h[m][f] (C-layout rows = 4 consecutive f -> one b64 write)
    #pragma unroll
    for (int ft = 0; ft < 2; ++ft){
      int flb = f0w + ft * 16 + lq * 4;
      f32x4 bv = *(const f32x4*)(b1 + ch * 64 + flb);
      #pragma unroll
      for (int mt = 0; mt < 2; ++mt){
        int m = m0w1 + mt * 16 + lr;
        bf16x4 hv;
        #pragma unroll
        for (int r = 0; r < 4; ++r){
          float p = acc1[ft][mt][r] + bv[r];
          float gl = 0.5f * p * (1.0f + erff(p * 0.70710678118654752f));
          hv[r] = (short)f2bf(gl);
        }
        *(bf16x4*)(smem + LDS_H + m * 144 + flb * 2) = hv;
      }
    }
    __syncthreads();

    // phase 2: acc2[c][m] += w2t[c][f] . h[m][f]
    #pragma unroll
    for (int ks = 0; ks < 2; ++ks){
      int kb = ks * 32 + lq * 8;
      bf16x8 hf[4], w2f[4];
      #pragma unroll
      for (int mt = 0; mt < 4; ++mt){
        int m = m0w2 + mt * 16 + lr;
        hf[mt] = *(const bf16x8*)(smem + LDS_H + m * 144 + kb * 2);
      }
      #pragma unroll
      for (int ct = 0; ct < 4; ++ct){
        int cc = c0w + ct * 16 + lr;
        w2f[ct] = *(const bf16x8*)(smem + LDS_W2 + (cc >> 1) * 272 + (cc & 1) * 128 + kb * 2);
      }
      #pragma unroll
      for (int ct = 0; ct < 4; ++ct)
        #pragma unroll
        for (int mt = 0; mt < 4; ++mt)
          acc2[ct][mt] = __builtin_amdgcn_mfma_f32_16x16x32_bf16(w2f[ct], hf[mt], acc2[ct][mt], 0, 0, 0);
    }
    __syncthreads();
  }

  // epilogue: + b2, write NCHW fp32 (16-lane m-contiguous = full 64B lines)
  #pragma unroll
  for (int ct = 0; ct < 4; ++ct){
    int cb = c0w + ct * 16 + lq * 4;
    f32x4 b2v = *(const f32x4*)(b2 + cb);
    #pragma unroll
    for (int mt = 0; mt < 4; ++mt){
      int m = m0w2 + mt * 16 + lr;
      unsigned pos = (unsigned)(blk * 128 + m);
      unsigned bimg = pos / 3136u;
      unsigned hw = pos - bimg * 3136u;
      float* op = out + ((long)bimg * 256 + cb) * 3136 + hw;
      #pragma unroll
      for (int r = 0; r < 4; ++r)
        op[r * 3136] = acc2[ct][mt][r] + b2v[r];
    }
  }
}

extern "C" void kernel_launch(void* const* d_in, const int* in_sizes, int n_in,
                              void* d_out, int out_size, void* d_ws, size_t ws_size,
                              hipStream_t stream){
  const float* x  = (const float*)d_in[0];
  const float* cw = (const float*)d_in[1];
  const float* cb = (const float*)d_in[2];
  const float* lg = (const float*)d_in[3];
  const float* lb = (const float*)d_in[4];
  const float* w1 = (const float*)d_in[5];
  const float* b1 = (const float*)d_in[6];
  const float* w2 = (const float*)d_in[7];
  const float* b2 = (const float*)d_in[8];
  float* out = (float*)d_out;

  // workspace: y (51,380,224 B) | w1t (524,288 B) | w2t (524,288 B)  = 50 MiB total
  unsigned short* y   = (unsigned short*)d_ws;
  unsigned short* w1t = (unsigned short*)((char*)d_ws + 51380224);
  unsigned short* w2t = (unsigned short*)((char*)d_ws + 51904512);

  hipLaunchKernelGGL(prep_kernel, dim3(2048), dim3(256), 0, stream, w1, w2, w1t, w2t);
  // conv writes t0 into d_out (scratch; fully overwritten by mlp_kernel later)
  hipLaunchKernelGGL(conv_kernel, dim3(8192), dim3(256), 0, stream, x, cw, cb, out);
  hipLaunchKernelGGL(ln_kernel,  dim3(392),  dim3(256), 0, stream, out, lg, lb, y);
  hipLaunchKernelGGL(mlp_kernel, dim3(784),  dim3(512), 0, stream, y, w1t, w2t, b1, b2, out);
}

// Round 2
// 580.577 us; speedup vs baseline: 1.1947x; 1.1947x over previous
//
#include <hip/hip_runtime.h>
#include <math.h>

#define CDIM 256
#define HW 3136
#define HID 1024

typedef __attribute__((ext_vector_type(4))) float f32x4;
typedef __attribute__((ext_vector_type(8))) short bf16x8;
typedef __attribute__((ext_vector_type(4))) short bf16x4;

__device__ __forceinline__ unsigned short f2bf(float f){
  unsigned int u = __float_as_uint(f);
  u += 0x7FFFu + ((u >> 16) & 1u);
  return (unsigned short)(u >> 16);
}

__device__ __forceinline__ void load_lds16(const void* g, void* l){
  __builtin_amdgcn_global_load_lds(
      (const __attribute__((address_space(1))) unsigned int*)g,
      (__attribute__((address_space(3))) unsigned int*)l, 16, 0, 0);
}

// ---------------- prep: w1t[f][c] = w1[c][f]; w2t[c][f] = w2[f][c]  (bf16)
__global__ __launch_bounds__(256) void prep_kernel(
    const float* __restrict__ w1, const float* __restrict__ w2,
    unsigned short* __restrict__ w1t, unsigned short* __restrict__ w2t){
  int i = blockIdx.x * 256 + threadIdx.x;
  if (i < 262144){
    int f = i >> 8, c = i & 255;
    w1t[i] = f2bf(w1[c * 1024 + f]);
  } else {
    int j = i - 262144;
    int c = j >> 10, f = j & 1023;
    w2t[j] = f2bf(w2[f * 256 + c]);
  }
}

// ---------------- depthwise 7x7 conv + bias -> t0 (NCHW fp32, = d_out scratch)
__global__ __launch_bounds__(256) void conv_kernel(
    const float* __restrict__ x, const float* __restrict__ cw,
    const float* __restrict__ cb, float* __restrict__ t0){
  int bc = blockIdx.x;          // b*256 + c
  int c = bc & 255;
  int t = threadIdx.x;
  int h = t >> 2;
  int w0 = (t & 3) * 14;
  float wt[49];
  #pragma unroll
  for (int k = 0; k < 49; ++k) wt[k] = cw[c * 49 + k];
  float bias = cb[c];
  if (h >= 56) return;
  const float* xp = x + (long)bc * HW;
  float acc[14];
  #pragma unroll
  for (int ww = 0; ww < 14; ++ww) acc[ww] = bias;
  #pragma unroll
  for (int i = 0; i < 7; ++i){
    int hh = h - 3 + i;
    if (hh >= 0 && hh < 56){
      float seg[20];
      #pragma unroll
      for (int k = 0; k < 20; ++k){
        int col = w0 - 3 + k;
        seg[k] = (col >= 0 && col < 56) ? xp[hh * 56 + col] : 0.0f;
      }
      #pragma unroll
      for (int j = 0; j < 7; ++j){
        #pragma unroll
        for (int ww = 0; ww < 14; ++ww)
          acc[ww] = fmaf(seg[ww + j], wt[i * 7 + j], acc[ww]);
      }
    }
  }
  float* op = t0 + (long)bc * HW + h * 56 + w0;
  #pragma unroll
  for (int ww = 0; ww < 14; ++ww) op[ww] = acc[ww];
}

// ---------------- LayerNorm over C, single pass -> y[pos][c] bf16
// block = 256 thr (4 waves), 64 positions; LDS tile [c][pos] (68-float rows)
__global__ __launch_bounds__(256) void ln_kernel(
    const float* __restrict__ t0, const float* __restrict__ lng,
    const float* __restrict__ lnb, unsigned short* __restrict__ y){
  __shared__ float tile[256 * 68];
  __shared__ float part_s[256];
  __shared__ float part_q[256];
  __shared__ float lg_s[256];
  __shared__ float lb_s[256];
  const int t = threadIdx.x, wv = t >> 6, lane = t & 63;
  const int pos0 = blockIdx.x * 64;                 // 3136 % 64 == 0: never straddles an image
  const int b = pos0 / HW;
  const int hw0 = pos0 - b * HW;
  const float* tp = t0 + (long)b * CDIM * HW + hw0;

  lg_s[t] = lng[t];
  lb_s[t] = lnb[t];

  float s = 0.f, q = 0.f;
  #pragma unroll 8
  for (int i = 0; i < 64; ++i){
    int c = wv * 64 + i;
    float v = tp[c * HW + lane];                    // coalesced 256B
    tile[c * 68 + lane] = v;                        // conflict-free (stride 68: 2-way max)
    s += v; q = fmaf(v, v, q);
  }
  part_s[wv * 64 + lane] = s;
  part_q[wv * 64 + lane] = q;
  __syncthreads();

  const int p = t >> 2, c0 = (t & 3) * 64;
  float S = part_s[p] + part_s[64 + p] + part_s[128 + p] + part_s[192 + p];
  float Q = part_q[p] + part_q[64 + p] + part_q[128 + p] + part_q[192 + p];
  float mu = S * (1.0f / 256.0f);
  float var = Q * (1.0f / 256.0f) - mu * mu;
  float rs = rsqrtf(var + 1e-6f);

  unsigned short* yp = y + (long)(pos0 + p) * 256 + c0;
  #pragma unroll
  for (int j = 0; j < 8; ++j){
    bf16x8 o;
    #pragma unroll
    for (int k = 0; k < 8; ++k){
      int c = c0 + j * 8 + k;
      float v = tile[c * 68 + p];
      o[k] = (short)f2bf((v - mu) * rs * lg_s[c] + lb_s[c]);
    }
    *(bf16x8*)(yp + j * 8) = o;
  }
}

// ---------------- fused MLP, BM=64, 256 thr, w1/w2 fragments from L2
// LDS: YA 32 groups x 1056B = 33792 ; H double buffer 2 x (64 x 144B) = 18432
#define LDS_H0 33792
#define MLP_LDS (33792 + 18432)
#define YA_ROW(m) ((((m) >> 1) * 1056) + (((m) & 1) * 512))

__global__ __launch_bounds__(256, 3) void mlp_kernel(
    const unsigned short* __restrict__ y, const unsigned short* __restrict__ w1t,
    const unsigned short* __restrict__ w2t, const float* __restrict__ b1,
    const float* __restrict__ b2, float* __restrict__ out){
  __shared__ __align__(16) unsigned char smem[MLP_LDS];
  const int t = threadIdx.x;
  const int wv = t >> 6, lane = t & 63;
  const int lr = lane & 15, lq = lane >> 4;
  const int blk = blockIdx.x;

  // stage y tile: rows blk*64..+63, 32 groups of 1024B (2 rows), +32B pad/group
  {
    const unsigned char* ybase = (const unsigned char*)(y + (long)blk * 64 * 256);
    #pragma unroll
    for (int r = 0; r < 8; ++r){
      int g = wv * 8 + r;
      load_lds16(ybase + g * 1024 + lane * 16, smem + g * 1056);
    }
  }

  f32x4 acc2[4][4];
  #pragma unroll
  for (int a = 0; a < 4; ++a)
    #pragma unroll
    for (int bb = 0; bb < 4; ++bb) acc2[a][bb] = (f32x4){0.f, 0.f, 0.f, 0.f};

  __syncthreads();   // staging barrier (drains global_load_lds)

  for (int ch = 0; ch < 16; ++ch){
    unsigned char* Hbuf = smem + LDS_H0 + (ch & 1) * 9216;

    // preload w1 fragments for this chunk (f = ch*64 + wv*16 + lr), L2-resident
    const unsigned short* w1p = w1t + (((long)ch * 64 + wv * 16 + lr) << 8);
    bf16x8 wf[8];
    #pragma unroll
    for (int ks = 0; ks < 8; ++ks)
      wf[ks] = *(const bf16x8*)(w1p + ks * 32 + lq * 8);

    // phase 1: P^T[f][m] = w1 . y^T  (A rows = f, B cols = m)
    f32x4 acc1[4];
    #pragma unroll
    for (int mt = 0; mt < 4; ++mt) acc1[mt] = (f32x4){0.f, 0.f, 0.f, 0.f};
    #pragma unroll
    for (int ks = 0; ks < 8; ++ks){
      bf16x8 yf[4];
      #pragma unroll
      for (int mt = 0; mt < 4; ++mt)
        yf[mt] = *(const bf16x8*)(smem + YA_ROW(mt * 16 + lr) + ks * 64 + lq * 16);
      #pragma unroll
      for (int mt = 0; mt < 4; ++mt)
        acc1[mt] = __builtin_amdgcn_mfma_f32_16x16x32_bf16(wf[ks], yf[mt], acc1[mt], 0, 0, 0);
    }

    // preload w2 fragments (issue before the barrier; latency overlaps it)
    bf16x8 w2f[2][4];
    #pragma unroll
    for (int ks2 = 0; ks2 < 2; ++ks2)
      #pragma unroll
      for (int ct = 0; ct < 4; ++ct)
        w2f[ks2][ct] = *(const bf16x8*)(w2t + (long)(wv * 64 + ct * 16 + lr) * 1024
                                        + ch * 64 + ks2 * 32 + lq * 8);

    // bias + exact GELU -> H[m][f_in_chunk]
    {
      f32x4 bv = *(const f32x4*)(b1 + ch * 64 + wv * 16 + lq * 4);
      #pragma unroll
      for (int mt = 0; mt < 4; ++mt){
        bf16x4 hv;
        #pragma unroll
        for (int r = 0; r < 4; ++r){
          float pv = acc1[mt][r] + bv[r];
          float gl = 0.5f * pv * (1.0f + erff(pv * 0.70710678118654752f));
          hv[r] = (short)f2bf(gl);
        }
        *(bf16x4*)(Hbuf + (mt * 16 + lr) * 144 + wv * 32 + lq * 8) = hv;
      }
    }
    __syncthreads();   // the only barrier per chunk (H write -> H read)

    // phase 2: acc2[c][m] += w2[c][f] . h[m][f]
    #pragma unroll
    for (int ks2 = 0; ks2 < 2; ++ks2){
      bf16x8 hf[4];
      #pragma unroll
      for (int mt = 0; mt < 4; ++mt)
        hf[mt] = *(const bf16x8*)(Hbuf + (mt * 16 + lr) * 144 + ks2 * 64 + lq * 16);
      #pragma unroll
      for (int ct = 0; ct < 4; ++ct)
        #pragma unroll
        for (int mt = 0; mt < 4; ++mt)
          acc2[ct][mt] = __builtin_amdgcn_mfma_f32_16x16x32_bf16(w2f[ks2][ct], hf[mt], acc2[ct][mt], 0, 0, 0);
    }
    // no trailing barrier: next chunk writes the other H buffer, and the
    // per-chunk barrier is a rendezvous (anything pre-barrier in any wave
    // happens-before anything post-barrier in any wave)
  }

  // epilogue: + b2, NCHW fp32 stores (16 m-consecutive lanes = 64B lines)
  #pragma unroll
  for (int ct = 0; ct < 4; ++ct){
    int cb = wv * 64 + ct * 16 + lq * 4;
    f32x4 b2v = *(const f32x4*)(b2 + cb);
    #pragma unroll
    for (int mt = 0; mt < 4; ++mt){
      int m = mt * 16 + lr;
      unsigned pos = (unsigned)(blk * 64 + m);
      unsigned bimg = pos / 3136u;
      unsigned hw = pos - bimg * 3136u;
      float* op = out + ((long)bimg * 256 + cb) * 3136 + hw;
      #pragma unroll
      for (int r = 0; r < 4; ++r)
        op[r * 3136] = acc2[ct][mt][r] + b2v[r];
    }
  }
}

extern "C" void kernel_launch(void* const* d_in, const int* in_sizes, int n_in,
                              void* d_out, int out_size, void* d_ws, size_t ws_size,
                              hipStream_t stream){
  const float* x  = (const float*)d_in[0];
  const float* cw = (const float*)d_in[1];
  const float* cb = (const float*)d_in[2];
  const float* lg = (const float*)d_in[3];
  const float* lb = (const float*)d_in[4];
  const float* w1 = (const float*)d_in[5];
  const float* b1 = (const float*)d_in[6];
  const float* w2 = (const float*)d_in[7];
  const float* b2 = (const float*)d_in[8];
  float* out = (float*)d_out;

  // workspace: y (51,380,224 B) | w1t (524,288 B) | w2t (524,288 B)
  unsigned short* y   = (unsigned short*)d_ws;
  unsigned short* w1t = (unsigned short*)((char*)d_ws + 51380224);
  unsigned short* w2t = (unsigned short*)((char*)d_ws + 51904512);

  hipLaunchKernelGGL(prep_kernel, dim3(2048), dim3(256), 0, stream, w1, w2, w1t, w2t);
  // conv writes t0 into d_out (scratch; fully overwritten by mlp_kernel later)
  hipLaunchKernelGGL(conv_kernel, dim3(8192), dim3(256), 0, stream, x, cw, cb, out);
  hipLaunchKernelGGL(ln_kernel,  dim3(1568), dim3(256), 0, stream, out, lg, lb, y);
  hipLaunchKernelGGL(mlp_kernel, dim3(1568), dim3(256), 0, stream, y, w1t, w2t, b1, b2, out);
}

// Round 3
// 528.832 us; speedup vs baseline: 1.3116x; 1.0978x over previous
//
#include <hip/hip_runtime.h>
#include <math.h>

#define CDIM 256
#define HW 3136
#define HID 1024

typedef __attribute__((ext_vector_type(4))) float f32x4;
typedef __attribute__((ext_vector_type(8))) short bf16x8;
typedef __attribute__((ext_vector_type(4))) short bf16x4;

__device__ __forceinline__ unsigned short f2bf(float f){
  unsigned int u = __float_as_uint(f);
  u += 0x7FFFu + ((u >> 16) & 1u);
  return (unsigned short)(u >> 16);
}

__device__ __forceinline__ void load_lds16(const void* g, void* l){
  __builtin_amdgcn_global_load_lds(
      (const __attribute__((address_space(1))) unsigned int*)g,
      (__attribute__((address_space(3))) unsigned int*)l, 16, 0, 0);
}

// ---------------- prep: w1t[f][c] = w1[c][f]; w2t[c][f] = w2[f][c]  (bf16)
__global__ __launch_bounds__(256) void prep_kernel(
    const float* __restrict__ w1, const float* __restrict__ w2,
    unsigned short* __restrict__ w1t, unsigned short* __restrict__ w2t){
  int i = blockIdx.x * 256 + threadIdx.x;
  if (i < 262144){
    int f = i >> 8, c = i & 255;
    w1t[i] = f2bf(w1[c * 1024 + f]);
  } else {
    int j = i - 262144;
    int c = j >> 10, f = j & 1023;
    w2t[j] = f2bf(w2[f * 256 + c]);
  }
}

// ---------------- fused depthwise 7x7 conv + bias + LayerNorm -> y[pos][c] bf16
// block = (b, h): 32*56 = 1792 blocks, 256 threads, thread = channel c.
// Conv: register sliding window over an aligned-float4-loaded row band.
// LN: LDS transpose tile [c][61] (pad 61: 29c+p bank -> conflict-free writes).
__global__ __launch_bounds__(256) void convln_kernel(
    const float* __restrict__ x, const float* __restrict__ cw,
    const float* __restrict__ cb, const float* __restrict__ lng,
    const float* __restrict__ lnb, unsigned short* __restrict__ y){
  __shared__ float tile[256 * 61];
  __shared__ float part_s[4][64];
  __shared__ float part_q[4][64];
  __shared__ float lg_s[256];
  __shared__ float lb_s[256];

  const int t = threadIdx.x;
  const int blk = blockIdx.x;
  const int b = blk / 56;
  const int h = blk - b * 56;
  const int c = t;

  lg_s[t] = lng[t];
  lb_s[t] = lnb[t];

  float acc[56];
  {
    float bias = cb[c];
    #pragma unroll
    for (int w = 0; w < 56; ++w) acc[w] = bias;
  }

  const float* xim = x + (long)(b * 256 + c) * HW;
  const float* cwc = cw + c * 49;
  for (int i = 0; i < 7; ++i){
    int hh = h - 3 + i;
    if (hh >= 0 && hh < 56){                    // uniform per block
      float seg[62];
      seg[0] = seg[1] = seg[2] = 0.f;
      seg[59] = seg[60] = seg[61] = 0.f;
      const float* xrow = xim + hh * 56;
      #pragma unroll
      for (int w4 = 0; w4 < 14; ++w4){
        f32x4 v = *(const f32x4*)(xrow + w4 * 4);
        seg[3 + w4 * 4 + 0] = v[0];
        seg[3 + w4 * 4 + 1] = v[1];
        seg[3 + w4 * 4 + 2] = v[2];
        seg[3 + w4 * 4 + 3] = v[3];
      }
      float wt7[7];
      #pragma unroll
      for (int j = 0; j < 7; ++j) wt7[j] = cwc[i * 7 + j];
      #pragma unroll
      for (int j = 0; j < 7; ++j){
        float wj = wt7[j];
        #pragma unroll
        for (int w = 0; w < 56; ++w)
          acc[w] = fmaf(seg[w + j], wj, acc[w]);
      }
    }
  }

  // write conv result to transpose tile (conflict-free: stride 61)
  #pragma unroll
  for (int p = 0; p < 56; ++p) tile[c * 61 + p] = acc[p];
  __syncthreads();

  // per-position sums over c (each wave: uniform c-quarter, lanes = position)
  {
    int p = t & 63; if (p > 55) p = 55;
    const int q = t >> 6;
    float s = 0.f, qq = 0.f;
    #pragma unroll 8
    for (int j = 0; j < 64; ++j){
      float v = tile[(q * 64 + j) * 61 + p];
      s += v; qq = fmaf(v, v, qq);
    }
    part_s[q][p] = s;
    part_q[q][p] = qq;
  }
  __syncthreads();

  // normalize + affine + bf16, write y[pos][c] with vector stores
  if (t < 224){
    const int p = t >> 2, c0 = (t & 3) * 64;
    float S = part_s[0][p] + part_s[1][p] + part_s[2][p] + part_s[3][p];
    float Q = part_q[0][p] + part_q[1][p] + part_q[2][p] + part_q[3][p];
    float mu = S * (1.0f / 256.0f);
    float var = Q * (1.0f / 256.0f) - mu * mu;
    float rs = rsqrtf(var + 1e-6f);
    unsigned short* yp = y + ((long)blk * 56 + p) * 256 + c0;
    #pragma unroll
    for (int j = 0; j < 8; ++j){
      bf16x8 o;
      #pragma unroll
      for (int k = 0; k < 8; ++k){
        int cc = c0 + j * 8 + k;
        float v = tile[cc * 61 + p];
        o[k] = (short)f2bf((v - mu) * rs * lg_s[cc] + lb_s[cc]);
      }
      *(bf16x8*)(yp + j * 8) = o;
    }
  }
}

// ---------------- fused MLP, BM=64, 256 thr, w1/w2 fragments from L2
// LDS: YA 32 groups x 1056B = 33792 ; H double buffer 2 x (64 x 144B) = 18432
#define LDS_H0 33792
#define MLP_LDS (33792 + 18432)
#define YA_ROW(m) ((((m) >> 1) * 1056) + (((m) & 1) * 512))

__global__ __launch_bounds__(256, 3) void mlp_kernel(
    const unsigned short* __restrict__ y, const unsigned short* __restrict__ w1t,
    const unsigned short* __restrict__ w2t, const float* __restrict__ b1,
    const float* __restrict__ b2, float* __restrict__ out){
  __shared__ __align__(16) unsigned char smem[MLP_LDS];
  const int t = threadIdx.x;
  const int wv = t >> 6, lane = t & 63;
  const int lr = lane & 15, lq = lane >> 4;
  const int blk = blockIdx.x;

  // stage y tile: rows blk*64..+63, 32 groups of 1024B (2 rows), +32B pad/group
  {
    const unsigned char* ybase = (const unsigned char*)(y + (long)blk * 64 * 256);
    #pragma unroll
    for (int r = 0; r < 8; ++r){
      int g = wv * 8 + r;
      load_lds16(ybase + g * 1024 + lane * 16, smem + g * 1056);
    }
  }

  f32x4 acc2[4][4];
  #pragma unroll
  for (int a = 0; a < 4; ++a)
    #pragma unroll
    for (int bb = 0; bb < 4; ++bb) acc2[a][bb] = (f32x4){0.f, 0.f, 0.f, 0.f};

  __syncthreads();   // staging barrier (drains global_load_lds)

  for (int ch = 0; ch < 16; ++ch){
    unsigned char* Hbuf = smem + LDS_H0 + (ch & 1) * 9216;

    // preload w1 fragments for this chunk (f = ch*64 + wv*16 + lr), L2-resident
    const unsigned short* w1p = w1t + (((long)ch * 64 + wv * 16 + lr) << 8);
    bf16x8 wf[8];
    #pragma unroll
    for (int ks = 0; ks < 8; ++ks)
      wf[ks] = *(const bf16x8*)(w1p + ks * 32 + lq * 8);

    // phase 1: P^T[f][m] = w1 . y^T  (A rows = f, B cols = m)
    f32x4 acc1[4];
    #pragma unroll
    for (int mt = 0; mt < 4; ++mt) acc1[mt] = (f32x4){0.f, 0.f, 0.f, 0.f};
    #pragma unroll
    for (int ks = 0; ks < 8; ++ks){
      bf16x8 yf[4];
      #pragma unroll
      for (int mt = 0; mt < 4; ++mt)
        yf[mt] = *(const bf16x8*)(smem + YA_ROW(mt * 16 + lr) + ks * 64 + lq * 16);
      #pragma unroll
      for (int mt = 0; mt < 4; ++mt)
        acc1[mt] = __builtin_amdgcn_mfma_f32_16x16x32_bf16(wf[ks], yf[mt], acc1[mt], 0, 0, 0);
    }

    // preload w2 fragments (issue before the barrier; latency overlaps it)
    bf16x8 w2f[2][4];
    #pragma unroll
    for (int ks2 = 0; ks2 < 2; ++ks2)
      #pragma unroll
      for (int ct = 0; ct < 4; ++ct)
        w2f[ks2][ct] = *(const bf16x8*)(w2t + (long)(wv * 64 + ct * 16 + lr) * 1024
                                        + ch * 64 + ks2 * 32 + lq * 8);

    // bias + tanh-GELU (max abs err ~3e-4) -> H[m][f_in_chunk]
    {
      f32x4 bv = *(const f32x4*)(b1 + ch * 64 + wv * 16 + lq * 4);
      #pragma unroll
      for (int mt = 0; mt < 4; ++mt){
        bf16x4 hv;
        #pragma unroll
        for (int r = 0; r < 4; ++r){
          float pv = acc1[mt][r] + bv[r];
          // gelu(p) ~= p * sigmoid(1.595769122*(p + 0.044715 p^3))
          float p2 = pv * pv;
          float u  = pv * fmaf(0.044715f, p2, 1.0f);
          float e  = __builtin_amdgcn_exp2f(-2.3022083f * u);
          float gl = pv * __builtin_amdgcn_rcpf(1.0f + e);
          hv[r] = (short)f2bf(gl);
        }
        *(bf16x4*)(Hbuf + (mt * 16 + lr) * 144 + wv * 32 + lq * 8) = hv;
      }
    }
    __syncthreads();   // the only barrier per chunk (H write -> H read)

    // phase 2: acc2[c][m] += w2[c][f] . h[m][f]
    #pragma unroll
    for (int ks2 = 0; ks2 < 2; ++ks2){
      bf16x8 hf[4];
      #pragma unroll
      for (int mt = 0; mt < 4; ++mt)
        hf[mt] = *(const bf16x8*)(Hbuf + (mt * 16 + lr) * 144 + ks2 * 64 + lq * 16);
      #pragma unroll
      for (int ct = 0; ct < 4; ++ct)
        #pragma unroll
        for (int mt = 0; mt < 4; ++mt)
          acc2[ct][mt] = __builtin_amdgcn_mfma_f32_16x16x32_bf16(w2f[ks2][ct], hf[mt], acc2[ct][mt], 0, 0, 0);
    }
  }

  // epilogue: + b2, NCHW fp32 stores (16 m-consecutive lanes = 64B lines)
  #pragma unroll
  for (int ct = 0; ct < 4; ++ct){
    int cb = wv * 64 + ct * 16 + lq * 4;
    f32x4 b2v = *(const f32x4*)(b2 + cb);
    #pragma unroll
    for (int mt = 0; mt < 4; ++mt){
      int m = mt * 16 + lr;
      unsigned pos = (unsigned)(blk * 64 + m);
      unsigned bimg = pos / 3136u;
      unsigned hw = pos - bimg * 3136u;
      float* op = out + ((long)bimg * 256 + cb) * 3136 + hw;
      #pragma unroll
      for (int r = 0; r < 4; ++r)
        op[r * 3136] = acc2[ct][mt][r] + b2v[r];
    }
  }
}

extern "C" void kernel_launch(void* const* d_in, const int* in_sizes, int n_in,
                              void* d_out, int out_size, void* d_ws, size_t ws_size,
                              hipStream_t stream){
  const float* x  = (const float*)d_in[0];
  const float* cw = (const float*)d_in[1];
  const float* cb = (const float*)d_in[2];
  const float* lg = (const float*)d_in[3];
  const float* lb = (const float*)d_in[4];
  const float* w1 = (const float*)d_in[5];
  const float* b1 = (const float*)d_in[6];
  const float* w2 = (const float*)d_in[7];
  const float* b2 = (const float*)d_in[8];
  float* out = (float*)d_out;

  // workspace: y (51,380,224 B) | w1t (524,288 B) | w2t (524,288 B)
  unsigned short* y   = (unsigned short*)d_ws;
  unsigned short* w1t = (unsigned short*)((char*)d_ws + 51380224);
  unsigned short* w2t = (unsigned short*)((char*)d_ws + 51904512);

  hipLaunchKernelGGL(prep_kernel,   dim3(2048), dim3(256), 0, stream, w1, w2, w1t, w2t);
  hipLaunchKernelGGL(convln_kernel, dim3(1792), dim3(256), 0, stream, x, cw, cb, lg, lb, y);
  hipLaunchKernelGGL(mlp_kernel,    dim3(1568), dim3(256), 0, stream, y, w1t, w2t, b1, b2, out);
}